// Round 18
// baseline (417.770 us; speedup 1.0000x reference)
//
#include <hip/hip_runtime.h>
#include <hip/hip_bf16.h>

#define TOK 4096
#define HD 1024
#define ID 512
#define NE 64
#define TK 8
#define CAP 1024
#define NROUTE 32768   // TOK*TK
#define NCHUNK 128     // NROUTE/256

typedef __attribute__((ext_vector_type(4))) float f32x4;
typedef __attribute__((ext_vector_type(8))) short s16x8;
typedef __attribute__((ext_vector_type(2))) __bf16 bf16x2;

__device__ __forceinline__ ushort f2bf(float f){
  uint u = __builtin_bit_cast(uint, f);
  u += 0x7fffu + ((u >> 16) & 1u);
  return (ushort)(u >> 16);
}
__device__ __forceinline__ float bf2f(ushort b){
  uint u = ((uint)b) << 16;
  return __builtin_bit_cast(float, u);
}
__device__ __forceinline__ uint2 f4_to_bf4(float4 v){
  bf16x2 p0; p0[0] = (__bf16)v.x; p0[1] = (__bf16)v.y;
  bf16x2 p1; p1[0] = (__bf16)v.z; p1[1] = (__bf16)v.w;
  uint2 r; r.x = __builtin_bit_cast(uint, p0); r.y = __builtin_bit_cast(uint, p1);
  return r;
}
__device__ __forceinline__ short bfs(float f){
  __bf16 h = (__bf16)f;
  return __builtin_bit_cast(short, h);
}
__device__ __forceinline__ s16x8 pack8(float4 a, float4 b){
  s16x8 r;
  r[0]=bfs(a.x); r[1]=bfs(a.y); r[2]=bfs(a.z); r[3]=bfs(a.w);
  r[4]=bfs(b.x); r[5]=bfs(b.y); r[6]=bfs(b.z); r[7]=bfs(b.w);
  return r;
}
__device__ __forceinline__ void gld16(void* lds, const void* g){
  __builtin_amdgcn_global_load_lds((const __attribute__((address_space(1))) unsigned int*)g,
                                   (__attribute__((address_space(3))) unsigned int*)lds, 16, 0, 0);
}

// ---------------- gating + X->bf16 byproduct ---------------------------------
__global__ __launch_bounds__(256)
void gating_kernel(const float* __restrict__ X, const float* __restrict__ GW,
                   ushort* __restrict__ Xbf,
                   int* __restrict__ topi, float* __restrict__ topw)
{
  __shared__ float xt[16][68];
  __shared__ float gt[64][68];
  __shared__ double ds[16][72];
  const int tid = threadIdx.x;
  const int tbase = blockIdx.x * 16;
  const int t = tid & 15, e0 = (tid >> 4) * 4;
  double acc[4] = {0.0, 0.0, 0.0, 0.0};
  for (int hc=0; hc<HD; hc+=64){
    { int r = tid >> 4, c4 = (tid & 15) * 4;
      float4 v = *(const float4*)(X + (size_t)(tbase+r)*HD + hc + c4);
      *(float4*)&xt[r][c4] = v;
      *(uint2*)(Xbf + (size_t)(tbase+r)*HD + hc + c4) = f4_to_bf4(v);   // fused cvtX
    }
    #pragma unroll
    for (int it=0; it<4; ++it){
      int idx = it*256 + tid;
      int r = idx >> 4, c4 = (idx & 15) * 4;
      *(float4*)&gt[r][c4] = *(const float4*)(GW + (size_t)r*HD + hc + c4);
    }
    __syncthreads();
    #pragma unroll
    for (int k4=0; k4<16; ++k4){
      float4 xv = *(const float4*)&xt[t][k4*4];
      #pragma unroll
      for (int j=0;j<4;++j){
        float4 gv = *(const float4*)&gt[e0+j][k4*4];
        acc[j] += (double)xv.x*(double)gv.x + (double)xv.y*(double)gv.y
                + (double)xv.z*(double)gv.z + (double)xv.w*(double)gv.w;
      }
    }
    __syncthreads();
  }
  #pragma unroll
  for (int j=0;j<4;++j) ds[t][e0+j] = acc[j];
  __syncthreads();
  if (tid < 16){
    int tt = tid;
    int idxs[8]; double vals[8]; double sum = 0.0;
    #pragma unroll
    for (int k=0;k<8;++k){
      double best = -1e300; int bi = 0;
      for (int e=0;e<NE;++e){ double v = ds[tt][e]; if (v > best){ best = v; bi = e; } }
      ds[tt][bi] = -1e300;
      double w = 1.0 / (1.0 + exp(-best));
      idxs[k] = bi; vals[k] = w; sum += w;
    }
    double inv = 1.0 / sum;
    #pragma unroll
    for (int k=0;k<8;++k){
      topi[(size_t)(tbase+tt)*TK + k] = idxs[k];
      topw[(size_t)(tbase+tt)*TK + k] = (float)(vals[k]*inv);
    }
  }
}

// ---------------- dispatch bookkeeping ---------------------------------------
__global__ __launch_bounds__(256)
void hist_kernel(const int* __restrict__ topi, int* __restrict__ ccnt){
  __shared__ int h[NE];
  const int tid = threadIdx.x;
  if (tid < NE) h[tid] = 0;
  __syncthreads();
  atomicAdd(&h[topi[blockIdx.x*256 + tid]], 1);
  __syncthreads();
  if (tid < NE) ccnt[blockIdx.x*NE + tid] = h[tid];
}

__global__ __launch_bounds__(64)
void scan_kernel(const int* __restrict__ ccnt, int* __restrict__ cbase,
                 int* __restrict__ cntC, int* __restrict__ ebase){
  const int e = threadIdx.x;
  int run = 0;
  for (int c=0;c<NCHUNK;++c){ cbase[c*NE+e] = run; run += ccnt[c*NE+e]; }
  cntC[e] = run < CAP ? run : CAP;
  __syncthreads();
  if (e == 0){
    int s = 0;
    for (int i=0;i<NE;++i){ ebase[i] = s; s += cntC[i]; }
    ebase[NE] = s;
  }
}

__global__ __launch_bounds__(64)
void assign_kernel(const int* __restrict__ topi, const int* __restrict__ cbase,
                   int* __restrict__ pos, int* __restrict__ rowlist){
  __shared__ int es[256];
  const int tid = threadIdx.x;
  const int c = blockIdx.x;
  for (int i=tid;i<256;i+=64) es[i] = topi[c*256+i];
  __syncthreads();
  const int e = tid;
  int cntr = cbase[c*NE+e];
  for (int j=0;j<256;++j){
    if (es[j] == e){
      int n = c*256+j;
      pos[n] = cntr;
      if (cntr < CAP) rowlist[e*CAP + cntr] = n;
      ++cntr;
    }
  }
}

// ---------------- gate/up GEMM + SwiGLU (v10: 512-thr dbuf, counted vmcnt) ---
// Routed blocks [0,1024): e x mt(4 x 256 rows) x nt(4 x 128 i-cols); shared
// [1024,1088). 8 waves 2Mx4N; wave = 128 rows x (32g+32u). A bf16 gld16 dbuf;
// B reg-staged fp32->bf16 dbuf. Counted s_waitcnt vmcnt(12): only the oldest
// A-tile drains at each barrier; 12 loads stay in flight (T4).
__global__ __launch_bounds__(512,1)
void gateup_kernel(const ushort* __restrict__ Xbf,
                   const float* __restrict__ WG, const float* __restrict__ WU,
                   const float* __restrict__ SWG, const float* __restrict__ SWU,
                   const int* __restrict__ rowlist, const int* __restrict__ cntC,
                   const int* __restrict__ ebase,
                   ushort* __restrict__ interm_r, ushort* __restrict__ interm_s)
{
  int nt, mt, cnt, outbase;
  const float *wg, *wu;
  ushort* interm;
  const bool shared_p = (blockIdx.x >= 1024u);
  if (shared_p){
    int b = blockIdx.x - 1024;
    nt = b & 3; mt = b >> 2; cnt = TOK; outbase = mt*256;
    wg = SWG + (size_t)nt*128*HD; wu = SWU + (size_t)nt*128*HD;
    interm = interm_s;
  } else {
    int x = blockIdx.x & 7; int rem = blockIdx.x >> 3;
    nt = rem & 3; mt = (rem >> 2) & 3; int e = ((rem >> 4) << 3) | x;  // XCD-local
    cnt = cntC[e];
    if (mt*256 >= cnt) return;
    outbase = ebase[e] + mt*256;
    const size_t wof = (size_t)e*ID*HD;
    wg = WG + wof + (size_t)nt*128*HD; wu = WU + wof + (size_t)nt*128*HD;
    interm = interm_r;
  }

  __shared__ ushort aL[2][128*128];  // 2 x 32KB: 128 lines(=256 rows) x 16 gran
  __shared__ ushort bL[2][128*128];  // 2 x 32KB: 256 B-rows (128g|128u)
  __shared__ int tokb[256];

  const int tid = threadIdx.x;
  if (tid < 256){
    int tokv;
    if (shared_p) tokv = mt*256 + tid;
    else {
      int x = blockIdx.x & 7; int rem = blockIdx.x >> 3;
      int e = ((rem >> 4) << 3) | x;
      tokv = (mt*256 + tid < cnt) ? (rowlist[e*CAP + mt*256 + tid] >> 3) : 0;
    }
    tokb[tid] = tokv;
  }
  __syncthreads();

  const int w = tid >> 6, l = tid & 63;
  const int wm = w >> 2, wn = w & 3;     // 2M x 4N
  const int fr = l & 15, fko = (l >> 4) * 8;

  uint aOff[4];
  #pragma unroll
  for (int j=0;j<4;++j){
    int f = j*512 + tid;
    int L = f >> 4, s = f & 15;
    int g = s ^ (L & 15);
    int r = 2*L + (g >> 3);
    aOff[j] = (uint)tokb[r]*HD + (uint)((g & 7)*8);
  }
  const float* bsrc[4]; int bDst[4];
  #pragma unroll
  for (int i=0;i<4;++i){
    int f = i*512 + tid;
    int L = f >> 4, s = f & 15;
    int g = s ^ (L & 15);
    int b = 2*L + (g >> 3);          // B-row [0,256)
    int n4 = b >> 6, r = b & 63;
    int mat = r >> 5, c = r & 31;
    const float* base = mat ? wu : wg;
    bsrc[i] = base + (size_t)(n4*32 + c)*HD + (g & 7)*8;
    bDst[i] = f*8;
  }

  f32x4 accg[8][2], accu[8][2];
  #pragma unroll
  for (int m=0;m<8;++m)
    #pragma unroll
    for (int c=0;c<2;++c){ accg[m][c] = (f32x4)0.0f; accu[m][c] = (f32x4)0.0f; }

  float4 br[8];

#define GU_LOADB(kc) { _Pragma("unroll") for (int i=0;i<4;++i){ \
    br[2*i]   = *(const float4*)(bsrc[i] + (kc)); \
    br[2*i+1] = *(const float4*)(bsrc[i] + (kc) + 4); } }
#define GU_WRITEB(BUF) { _Pragma("unroll") for (int i=0;i<4;++i) \
    *(s16x8*)&bL[BUF][bDst[i]] = pack8(br[2*i], br[2*i+1]); }
#define GU_STAGEA(BUF, kc) { _Pragma("unroll") for (int j=0;j<4;++j) \
    gld16(&aL[BUF][(j*512 + w*64)*8], Xbf + aOff[j] + (kc)); }
#define GU_COMPUTE(BUF) { _Pragma("unroll") for (int ks=0;ks<2;++ks){ \
    int gk = ks*4 + (fko>>3); \
    s16x8 bg[2], bu[2]; \
    _Pragma("unroll") for (int cg=0;cg<2;++cg){ \
      int b1 = wn*64 + cg*16 + fr;      int L1 = b1>>1, g1 = ((b1&1)<<3)|gk; \
      bg[cg] = *(const s16x8*)&bL[BUF][L1*128 + (g1^(L1&15))*8]; \
      int b2 = wn*64 + 32 + cg*16 + fr; int L2 = b2>>1, g2 = ((b2&1)<<3)|gk; \
      bu[cg] = *(const s16x8*)&bL[BUF][L2*128 + (g2^(L2&15))*8]; \
    } \
    _Pragma("unroll") for (int mb=0;mb<8;++mb){ \
      int r = wm*128 + mb*16 + fr; \
      int L = r>>1, g = ((r&1)<<3)|gk; \
      s16x8 a = *(const s16x8*)&aL[BUF][L*128 + (g^(L&15))*8]; \
      _Pragma("unroll") for (int cg=0;cg<2;++cg){ \
        accg[mb][cg] = __builtin_amdgcn_mfma_f32_16x16x32_bf16(a, bg[cg], accg[mb][cg],0,0,0); \
        accu[mb][cg] = __builtin_amdgcn_mfma_f32_16x16x32_bf16(a, bu[cg], accu[mb][cg],0,0,0); \
      } } } }

  // prologue: tile 0 fully staged (full drain once)
  GU_LOADB(0);
  GU_STAGEA(0, 0);
  GU_WRITEB(0);
  __syncthreads();

  for (int t=0; t<15; ++t){
    const int cur = t & 1, nxt = cur ^ 1;
    GU_LOADB((t+1)*64);                    // 8 vmem (newest)
    GU_STAGEA(nxt, (t+1)*64);              // 4 gld16
    asm volatile("s_waitcnt vmcnt(12)" ::: "memory");   // drain only A(t)
    __builtin_amdgcn_sched_barrier(0);
    __builtin_amdgcn_s_barrier();
    GU_COMPUTE(cur);
    GU_WRITEB(nxt);                        // compiler waits br vmem
    asm volatile("s_waitcnt lgkmcnt(0)" ::: "memory");
    __builtin_amdgcn_sched_barrier(0);
    __builtin_amdgcn_s_barrier();
  }
  asm volatile("s_waitcnt vmcnt(0)" ::: "memory");
  __builtin_amdgcn_sched_barrier(0);
  __builtin_amdgcn_s_barrier();
  GU_COMPUTE(1);                           // t = 15
#undef GU_LOADB
#undef GU_WRITEB
#undef GU_STAGEA
#undef GU_COMPUTE

  const int rq = (l >> 4) * 4;
  #pragma unroll
  for (int mb=0;mb<8;++mb){
    #pragma unroll
    for (int q=0;q<4;++q){
      int rloc = wm*128 + mb*16 + rq + q;
      if (mt*256 + rloc >= cnt) continue;
      size_t orow = (size_t)(outbase + rloc);
      #pragma unroll
      for (int cg=0;cg<2;++cg){
        float g = accg[mb][cg][q], u = accu[mb][cg][q];
        float sv = g / (1.0f + __expf(-g)) * u;   // silu(g)*u
        interm[orow*ID + (size_t)(nt*128 + wn*32 + cg*16 + fr)] = f2bf(sv);
      }
    }
  }
}

// ---------------- down GEMM (v10: 512-thr dbuf, counted vmcnt) ---------------
// Routed blocks [0,1024): e x mt(4 x 256 rows) x nt(4 x 256 out-cols); shared
// [1024,1088). 8 waves 2Mx4N; wave = 128 x 64. K=512 (8 steps).
__global__ __launch_bounds__(512,1)
void down_kernel(const ushort* __restrict__ interm_r, const ushort* __restrict__ interm_s,
                 const float* __restrict__ WD, const float* __restrict__ SWD,
                 const int* __restrict__ cntC, const int* __restrict__ ebase,
                 ushort* __restrict__ out_rows, float* __restrict__ outf)
{
  int nt, mt, cnt, abase;
  const ushort* A;
  const float* wd;
  const bool shared_p = (blockIdx.x >= 1024u);
  if (shared_p){
    int b = blockIdx.x - 1024;
    nt = b & 3; mt = b >> 2; cnt = TOK; abase = mt*256;
    A = interm_s + (size_t)abase*ID;
    wd = SWD + (size_t)nt*256*ID;
  } else {
    int x = blockIdx.x & 7; int rem = blockIdx.x >> 3;
    nt = rem & 3; mt = (rem >> 2) & 3; int e = ((rem >> 4) << 3) | x;
    cnt = cntC[e];
    if (mt*256 >= cnt) return;
    abase = ebase[e] + mt*256;
    A = interm_r + (size_t)abase*ID;
    wd = WD + (size_t)e*HD*ID + (size_t)nt*256*ID;
  }

  __shared__ ushort aL[2][128*128];
  __shared__ ushort bL[2][128*128];

  const int tid = threadIdx.x;
  const int w = tid >> 6, l = tid & 63;
  const int wm = w >> 2, wn = w & 3;
  const int fr = l & 15, fko = (l >> 4) * 8;

  uint aOff[4];
  #pragma unroll
  for (int j=0;j<4;++j){
    int f = j*512 + tid;
    int L = f >> 4, s = f & 15;
    int g = s ^ (L & 15);
    int r = 2*L + (g >> 3);
    aOff[j] = (uint)r*ID + (uint)((g & 7)*8);
  }
  const float* bsrc[4]; int bDst[4];
  #pragma unroll
  for (int i=0;i<4;++i){
    int f = i*512 + tid;
    int L = f >> 4, s = f & 15;
    int g = s ^ (L & 15);
    int b = 2*L + (g >> 3);          // out-col within block [0,256)
    bsrc[i] = wd + (size_t)b*ID + (g & 7)*8;
    bDst[i] = f*8;
  }

  f32x4 acc[8][4];
  #pragma unroll
  for (int m=0;m<8;++m)
    #pragma unroll
    for (int c=0;c<4;++c) acc[m][c] = (f32x4)0.0f;

  float4 br[8];

#define DN_LOADB(kc) { _Pragma("unroll") for (int i=0;i<4;++i){ \
    br[2*i]   = *(const float4*)(bsrc[i] + (kc)); \
    br[2*i+1] = *(const float4*)(bsrc[i] + (kc) + 4); } }
#define DN_WRITEB(BUF) { _Pragma("unroll") for (int i=0;i<4;++i) \
    *(s16x8*)&bL[BUF][bDst[i]] = pack8(br[2*i], br[2*i+1]); }
#define DN_STAGEA(BUF, kc) { _Pragma("unroll") for (int j=0;j<4;++j) \
    gld16(&aL[BUF][(j*512 + w*64)*8], A + aOff[j] + (kc)); }
#define DN_COMPUTE(BUF) { _Pragma("unroll") for (int ks=0;ks<2;++ks){ \
    int gk = ks*4 + (fko>>3); \
    s16x8 bd[4]; \
    _Pragma("unroll") for (int cg=0;cg<4;++cg){ \
      int b1 = wn*64 + cg*16 + fr; int L1 = b1>>1, g1 = ((b1&1)<<3)|gk; \
      bd[cg] = *(const s16x8*)&bL[BUF][L1*128 + (g1^(L1&15))*8]; \
    } \
    _Pragma("unroll") for (int mb=0;mb<8;++mb){ \
      int r = wm*128 + mb*16 + fr; \
      int L = r>>1, g = ((r&1)<<3)|gk; \
      s16x8 a = *(const s16x8*)&aL[BUF][L*128 + (g^(L&15))*8]; \
      _Pragma("unroll") for (int cg=0;cg<4;++cg) \
        acc[mb][cg] = __builtin_amdgcn_mfma_f32_16x16x32_bf16(a, bd[cg], acc[mb][cg],0,0,0); \
    } } }

  DN_LOADB(0);
  DN_STAGEA(0, 0);
  DN_WRITEB(0);
  __syncthreads();

  for (int t=0; t<7; ++t){
    const int cur = t & 1, nxt = cur ^ 1;
    DN_LOADB((t+1)*64);
    DN_STAGEA(nxt, (t+1)*64);
    asm volatile("s_waitcnt vmcnt(12)" ::: "memory");
    __builtin_amdgcn_sched_barrier(0);
    __builtin_amdgcn_s_barrier();
    DN_COMPUTE(cur);
    DN_WRITEB(nxt);
    asm volatile("s_waitcnt lgkmcnt(0)" ::: "memory");
    __builtin_amdgcn_sched_barrier(0);
    __builtin_amdgcn_s_barrier();
  }
  asm volatile("s_waitcnt vmcnt(0)" ::: "memory");
  __builtin_amdgcn_sched_barrier(0);
  __builtin_amdgcn_s_barrier();
  DN_COMPUTE(1);                           // t = 7
#undef DN_LOADB
#undef DN_WRITEB
#undef DN_STAGEA
#undef DN_COMPUTE

  const int rq = (l >> 4) * 4;
  #pragma unroll
  for (int mb=0;mb<8;++mb){
    #pragma unroll
    for (int q=0;q<4;++q){
      int rloc = wm*128 + mb*16 + rq + q;
      if (mt*256 + rloc >= cnt) continue;
      #pragma unroll
      for (int cg=0;cg<4;++cg){
        float v = acc[mb][cg][q];
        int colg = nt*256 + wn*64 + cg*16 + fr;
        if (shared_p) outf[(size_t)(mt*256 + rloc)*HD + colg] = v;
        else          out_rows[(size_t)(abase + rloc)*HD + colg] = f2bf(v);
      }
    }
  }
}

// ---------------- combine: out += sum_k topw * routed_row --------------------
__global__ __launch_bounds__(256)
void combine_kernel(const int* __restrict__ topi, const float* __restrict__ topw,
                    const int* __restrict__ pos, const int* __restrict__ ebase,
                    const ushort* __restrict__ out_rows, float* __restrict__ out)
{
  const int t = blockIdx.x;
  const int tid = threadIdx.x;
  __shared__ int rws[TK];
  __shared__ float wts[TK];
  if (tid < TK){
    int e = topi[(size_t)t*TK + tid];
    int p = pos[(size_t)t*TK + tid];
    rws[tid] = (p < CAP) ? (ebase[e] + p) : -1;
    wts[tid] = topw[(size_t)t*TK + tid];
  }
  __syncthreads();
  const int h0 = tid * 4;
  float4 acc = *(float4*)(out + (size_t)t*HD + h0);
  #pragma unroll
  for (int k=0;k<TK;++k){
    int r = rws[k];
    if (r < 0) continue;
    ushort4 v = *(const ushort4*)(out_rows + (size_t)r*HD + h0);
    float wk = wts[k];
    acc.x += wk*bf2f(v.x); acc.y += wk*bf2f(v.y);
    acc.z += wk*bf2f(v.z); acc.w += wk*bf2f(v.w);
  }
  *(float4*)(out + (size_t)t*HD + h0) = acc;
}

// ---------------- launch ------------------------------------------------------
extern "C" void kernel_launch(void* const* d_in, const int* in_sizes, int n_in,
                              void* d_out, int out_size, void* d_ws, size_t ws_size,
                              hipStream_t stream)
{
  (void)in_sizes; (void)n_in; (void)out_size; (void)ws_size;
  const float* X   = (const float*)d_in[0];
  const float* GW  = (const float*)d_in[1];
  const float* SWG = (const float*)d_in[2];
  const float* SWU = (const float*)d_in[3];
  const float* SWD = (const float*)d_in[4];
  const float* EWG = (const float*)d_in[5];
  const float* EWU = (const float*)d_in[6];
  const float* EWD = (const float*)d_in[7];
  float* OUT = (float*)d_out;

  char* p = (char*)d_ws;
  int*    topi    = (int*)p;      p += (size_t)NROUTE*4;
  float*  topw    = (float*)p;    p += (size_t)NROUTE*4;
  int*    pos     = (int*)p;      p += (size_t)NROUTE*4;
  int*    ccnt    = (int*)p;      p += (size_t)NCHUNK*NE*4;
  int*    cbase   = (int*)p;      p += (size_t)NCHUNK*NE*4;
  int*    cntC    = (int*)p;      p += 256;
  int*    ebase   = (int*)p;      p += 512;
  int*    rowlist = (int*)p;      p += (size_t)NE*CAP*4;
  ushort* Xbf     = (ushort*)p;   p += (size_t)TOK*HD*2;
  ushort* interm_r= (ushort*)p;   p += (size_t)(NROUTE+256)*ID*2;
  ushort* interm_s= (ushort*)p;   p += (size_t)TOK*ID*2;
  ushort* out_rows= (ushort*)p;   p += (size_t)NROUTE*HD*2;

  gating_kernel<<<256, 256, 0, stream>>>(X, GW, Xbf, topi, topw);
  hist_kernel<<<NCHUNK, 256, 0, stream>>>(topi, ccnt);
  scan_kernel<<<1, 64, 0, stream>>>(ccnt, cbase, cntC, ebase);
  assign_kernel<<<NCHUNK, 64, 0, stream>>>(topi, cbase, pos, rowlist);

  gateup_kernel<<<1088, 512, 0, stream>>>(Xbf, EWG, EWU, SWG, SWU,
                                          rowlist, cntC, ebase, interm_r, interm_s);
  down_kernel<<<1088, 512, 0, stream>>>(interm_r, interm_s, EWD, SWD,
                                        cntC, ebase, out_rows, OUT);

  combine_kernel<<<TOK, 256, 0, stream>>>(topi, topw, pos, ebase, out_rows, OUT);
}

// Round 19
// 356.197 us; speedup vs baseline: 1.1729x; 1.1729x over previous
//
#include <hip/hip_runtime.h>
#include <hip/hip_bf16.h>

#define TOK 4096
#define HD 1024
#define ID 512
#define NE 64
#define TK 8
#define CAP 1024
#define NROUTE 32768   // TOK*TK
#define NCHUNK 128     // NROUTE/256

typedef __attribute__((ext_vector_type(4))) float f32x4;
typedef __attribute__((ext_vector_type(8))) short s16x8;
typedef __attribute__((ext_vector_type(2))) __bf16 bf16x2;

__device__ __forceinline__ ushort f2bf(float f){
  uint u = __builtin_bit_cast(uint, f);
  u += 0x7fffu + ((u >> 16) & 1u);
  return (ushort)(u >> 16);
}
__device__ __forceinline__ float bf2f(ushort b){
  uint u = ((uint)b) << 16;
  return __builtin_bit_cast(float, u);
}
__device__ __forceinline__ uint2 f4_to_bf4(float4 v){
  bf16x2 p0; p0[0] = (__bf16)v.x; p0[1] = (__bf16)v.y;
  bf16x2 p1; p1[0] = (__bf16)v.z; p1[1] = (__bf16)v.w;
  uint2 r; r.x = __builtin_bit_cast(uint, p0); r.y = __builtin_bit_cast(uint, p1);
  return r;
}
__device__ __forceinline__ short bfs(float f){
  __bf16 h = (__bf16)f;
  return __builtin_bit_cast(short, h);
}
__device__ __forceinline__ s16x8 pack8(f32x4 a, f32x4 b){
  s16x8 r;
  r[0]=bfs(a[0]); r[1]=bfs(a[1]); r[2]=bfs(a[2]); r[3]=bfs(a[3]);
  r[4]=bfs(b[0]); r[5]=bfs(b[1]); r[6]=bfs(b[2]); r[7]=bfs(b[3]);
  return r;
}
__device__ __forceinline__ void gld16(void* lds, const void* g){
  __builtin_amdgcn_global_load_lds((const __attribute__((address_space(1))) unsigned int*)g,
                                   (__attribute__((address_space(3))) unsigned int*)lds, 16, 0, 0);
}

// ---------------- gating + X->bf16 byproduct ---------------------------------
// 256 blocks x 16 tokens; fp64 accumulate; writes Xbf while staging X.
__global__ __launch_bounds__(256)
void gating_kernel(const float* __restrict__ X, const float* __restrict__ GW,
                   ushort* __restrict__ Xbf,
                   int* __restrict__ topi, float* __restrict__ topw)
{
  __shared__ float xt[16][68];
  __shared__ float gt[64][68];
  __shared__ double ds[16][72];
  const int tid = threadIdx.x;
  const int tbase = blockIdx.x * 16;
  const int t = tid & 15, e0 = (tid >> 4) * 4;
  double acc[4] = {0.0, 0.0, 0.0, 0.0};
  for (int hc=0; hc<HD; hc+=64){
    { int r = tid >> 4, c4 = (tid & 15) * 4;
      float4 v = *(const float4*)(X + (size_t)(tbase+r)*HD + hc + c4);
      *(float4*)&xt[r][c4] = v;
      *(uint2*)(Xbf + (size_t)(tbase+r)*HD + hc + c4) = f4_to_bf4(v);   // fused cvtX
    }
    #pragma unroll
    for (int it=0; it<4; ++it){
      int idx = it*256 + tid;
      int r = idx >> 4, c4 = (idx & 15) * 4;
      *(float4*)&gt[r][c4] = *(const float4*)(GW + (size_t)r*HD + hc + c4);
    }
    __syncthreads();
    #pragma unroll
    for (int k4=0; k4<16; ++k4){
      float4 xv = *(const float4*)&xt[t][k4*4];
      #pragma unroll
      for (int j=0;j<4;++j){
        float4 gv = *(const float4*)&gt[e0+j][k4*4];
        acc[j] += (double)xv.x*(double)gv.x + (double)xv.y*(double)gv.y
                + (double)xv.z*(double)gv.z + (double)xv.w*(double)gv.w;
      }
    }
    __syncthreads();
  }
  #pragma unroll
  for (int j=0;j<4;++j) ds[t][e0+j] = acc[j];
  __syncthreads();
  if (tid < 16){
    int tt = tid;
    int idxs[8]; double vals[8]; double sum = 0.0;
    #pragma unroll
    for (int k=0;k<8;++k){
      double best = -1e300; int bi = 0;
      for (int e=0;e<NE;++e){ double v = ds[tt][e]; if (v > best){ best = v; bi = e; } }
      ds[tt][bi] = -1e300;
      double w = 1.0 / (1.0 + exp(-best));
      idxs[k] = bi; vals[k] = w; sum += w;
    }
    double inv = 1.0 / sum;
    #pragma unroll
    for (int k=0;k<8;++k){
      topi[(size_t)(tbase+tt)*TK + k] = idxs[k];
      topw[(size_t)(tbase+tt)*TK + k] = (float)(vals[k]*inv);
    }
  }
}

// ---------------- dispatch bookkeeping ---------------------------------------
__global__ __launch_bounds__(256)
void hist_kernel(const int* __restrict__ topi, int* __restrict__ ccnt){
  __shared__ int h[NE];
  const int tid = threadIdx.x;
  if (tid < NE) h[tid] = 0;
  __syncthreads();
  atomicAdd(&h[topi[blockIdx.x*256 + tid]], 1);
  __syncthreads();
  if (tid < NE) ccnt[blockIdx.x*NE + tid] = h[tid];
}

__global__ __launch_bounds__(64)
void scan_kernel(const int* __restrict__ ccnt, int* __restrict__ cbase,
                 int* __restrict__ cntC, int* __restrict__ ebase){
  const int e = threadIdx.x;
  int run = 0;
  for (int c=0;c<NCHUNK;++c){ cbase[c*NE+e] = run; run += ccnt[c*NE+e]; }
  cntC[e] = run < CAP ? run : CAP;
  __syncthreads();
  if (e == 0){
    int s = 0;
    for (int i=0;i<NE;++i){ ebase[i] = s; s += cntC[i]; }
    ebase[NE] = s;
  }
}

__global__ __launch_bounds__(64)
void assign_kernel(const int* __restrict__ topi, const int* __restrict__ cbase,
                   int* __restrict__ pos, int* __restrict__ rowlist){
  __shared__ int es[256];
  const int tid = threadIdx.x;
  const int c = blockIdx.x;
  for (int i=tid;i<256;i+=64) es[i] = topi[c*256+i];
  __syncthreads();
  const int e = tid;
  int cntr = cbase[c*NE+e];
  for (int j=0;j<256;++j){
    if (es[j] == e){
      int n = c*256+j;
      pos[n] = cntr;
      if (cntr < CAP) rowlist[e*CAP + cntr] = n;
      ++cntr;
    }
  }
}

// ---------------- merged gate/up GEMM + fused SwiGLU (R10 core) --------------
// Blocks [0,4096): routed (XCD-local). Blocks [4096,4352): shared expert.
// Core: 128 rows x 64 i-cols, 4 waves 2x2; A bf16 gld16 (16KB), B fp32 gld16
// (32KB), 16-slot XOR both; 2-barrier loop. LDS-transpose epilogue ->
// coalesced uint4 stores.
__global__ __launch_bounds__(256,2)
void gateup_kernel(const ushort* __restrict__ Xbf,
                   const float* __restrict__ WG, const float* __restrict__ WU,
                   const float* __restrict__ SWG, const float* __restrict__ SWU,
                   const int* __restrict__ rowlist, const int* __restrict__ cntC,
                   const int* __restrict__ ebase,
                   ushort* __restrict__ interm_r, ushort* __restrict__ interm_s)
{
  int nt, mt, cnt, outbase;
  const float *wg, *wu;
  ushort* interm;
  const bool shared_p = (blockIdx.x >= 4096u);
  const int e_rl = shared_p ? 0 : ((((blockIdx.x >> 3) >> 6) << 3) | (blockIdx.x & 7));
  if (shared_p){
    int b = blockIdx.x - 4096;
    nt = b & 7; mt = b >> 3; cnt = TOK; outbase = mt*128;
    wg = SWG + (size_t)nt*64*HD; wu = SWU + (size_t)nt*64*HD;
    interm = interm_s;
  } else {
    int rem = blockIdx.x >> 3;
    nt = rem & 7; mt = (rem >> 3) & 7;
    cnt = cntC[e_rl];
    if (mt*128 >= cnt) return;
    outbase = ebase[e_rl] + mt*128;
    const size_t wof = (size_t)e_rl*ID*HD;
    wg = WG + wof + (size_t)nt*64*HD; wu = WU + wof + (size_t)nt*64*HD;
    interm = interm_r;
  }

  __shared__ ushort aL[64*128];   // 16KB: 64 lines (=128 rows) x 16 granules
  __shared__ float  bF[128*64];   // 32KB fp32 (reused as epilogue transpose buf)
  __shared__ int tokb[128];

  const int tid = threadIdx.x;
  if (tid < 128){
    int tokv;
    if (shared_p) tokv = mt*128 + tid;
    else tokv = (mt*128 + tid < cnt) ? (rowlist[e_rl*CAP + mt*128 + tid] >> 3) : 0;
    tokb[tid] = tokv;
  }
  __syncthreads();

  const int w = tid >> 6, l = tid & 63;
  const int wm = w >> 1, wn = w & 1;
  const int fr = l & 15, fko = (l >> 4) * 8;

  const ushort* aSrc[4];
  #pragma unroll
  for (int j=0;j<4;++j){
    int f = j*256 + tid;
    int L = f >> 4, s = f & 15;
    int g = s ^ (L & 15);
    int row = 2*L + (g >> 3);
    aSrc[j] = Xbf + (size_t)tokb[row]*HD + (g & 7)*8;
  }
  const float* bSrc[8];
  #pragma unroll
  for (int j=0;j<8;++j){
    int f = j*256 + tid;
    int R = f >> 4, s = f & 15;
    int g = s ^ (R & 15);
    const float* base = (j < 4) ? wg : wu;
    int r2 = (j < 4) ? R : (R - 64);
    bSrc[j] = base + (size_t)r2*HD + g*4;
  }

  f32x4 accg[4][2], accu[4][2];
  #pragma unroll
  for (int i=0;i<4;++i)
    #pragma unroll
    for (int j=0;j<2;++j){ accg[i][j] = (f32x4)0.0f; accu[i][j] = (f32x4)0.0f; }

  auto stage = [&](int kc){
    #pragma unroll
    for (int j=0;j<4;++j) gld16(aL + (size_t)(j*256 + w*64)*8, aSrc[j] + kc);
    #pragma unroll
    for (int j=0;j<8;++j) gld16(bF + (size_t)(j*256 + w*64)*4, bSrc[j] + kc);
  };

  stage(0);
  for (int kc=0; kc<HD; kc+=64){
    __syncthreads();   // drains vmcnt: staged tile visible
    #pragma unroll
    for (int ks=0; ks<2; ++ks){
      s16x8 a[4];
      #pragma unroll
      for (int mb=0; mb<4; ++mb){
        int r = wm*64 + mb*16 + fr;
        int agl = ks*4 + (fko >> 3);
        int g = ((r & 1) << 3) | agl;
        int L = r >> 1;
        int gs = g ^ (L & 15);
        a[mb] = *(const s16x8*)&aL[L*128 + gs*8];
      }
      #pragma unroll
      for (int cg=0; cg<2; ++cg){
        int Rg = wn*32 + cg*16 + fr;
        int gl0 = ks*8 + (fko >> 2);
        int x0 = Rg*64 + ((gl0 ^ (Rg & 15)) * 4);
        int x1 = Rg*64 + (((gl0+1) ^ (Rg & 15)) * 4);
        s16x8 bg = pack8(*(const f32x4*)&bF[x0], *(const f32x4*)&bF[x1]);
        int Ru = 64 + wn*32 + cg*16 + fr;
        int y0 = Ru*64 + ((gl0 ^ (Ru & 15)) * 4);
        int y1 = Ru*64 + (((gl0+1) ^ (Ru & 15)) * 4);
        s16x8 bu = pack8(*(const f32x4*)&bF[y0], *(const f32x4*)&bF[y1]);
        #pragma unroll
        for (int mb=0; mb<4; ++mb){
          accg[mb][cg] = __builtin_amdgcn_mfma_f32_16x16x32_bf16(a[mb], bg, accg[mb][cg], 0, 0, 0);
          accu[mb][cg] = __builtin_amdgcn_mfma_f32_16x16x32_bf16(a[mb], bu, accu[mb][cg], 0, 0, 0);
        }
      }
    }
    __syncthreads();
    if (kc + 64 < HD) stage(kc + 64);
  }

  // epilogue: scatter bf16 into LDS (chunk-XOR swizzled), then coalesced flush
  const int rq = (l >> 4) * 4;
  ushort* sm = (ushort*)bF;               // 128 rows x 64 cols (16KB of 32KB)
  #pragma unroll
  for (int mb=0; mb<4; ++mb){
    #pragma unroll
    for (int q=0; q<4; ++q){
      int rloc = wm*64 + mb*16 + rq + q;
      #pragma unroll
      for (int cg=0; cg<2; ++cg){
        float g = accg[mb][cg][q], u = accu[mb][cg][q];
        float sv = g / (1.0f + __expf(-g)) * u;   // silu(g)*u
        int col = wn*32 + cg*16 + fr;
        int chunk = col >> 3;
        sm[rloc*64 + ((chunk ^ (rloc & 7)) << 3) + (col & 7)] = f2bf(sv);
      }
    }
  }
  __syncthreads();
  #pragma unroll
  for (int i=0;i<4;++i){
    int idx = i*256 + tid;
    int row = idx >> 3, j = idx & 7;
    if (mt*128 + row < cnt){
      uint4 v = *(const uint4*)&sm[row*64 + ((j ^ (row & 7)) << 3)];
      *(uint4*)(interm + (size_t)(outbase + row)*ID + nt*64 + j*8) = v;
    }
  }
}

// ---------------- merged down GEMM (R10 core) --------------------------------
// Blocks [0,4096): routed -> out_rows bf16 (LDS-transpose epilogue).
// Blocks [4096,4352): shared -> OUT fp32 (scalar stores).
__global__ __launch_bounds__(256,2)
void down_kernel(const ushort* __restrict__ interm_r, const ushort* __restrict__ interm_s,
                 const float* __restrict__ WD, const float* __restrict__ SWD,
                 const int* __restrict__ cntC, const int* __restrict__ ebase,
                 ushort* __restrict__ out_rows, float* __restrict__ outf)
{
  int nt, mt, cnt, abase;
  const ushort* A;
  const float* wd;
  const bool shared_p = (blockIdx.x >= 4096u);
  if (shared_p){
    int b = blockIdx.x - 4096;
    nt = b & 7; mt = b >> 3; cnt = TOK; abase = mt*128;
    A = interm_s + (size_t)abase*ID;
    wd = SWD + (size_t)nt*128*ID;
  } else {
    int x = blockIdx.x & 7; int rem = blockIdx.x >> 3;
    nt = rem & 7; mt = (rem >> 3) & 7; int e = ((rem >> 6) << 3) | x;
    cnt = cntC[e];
    if (mt*128 >= cnt) return;
    abase = ebase[e] + mt*128;
    A = interm_r + (size_t)abase*ID;
    wd = WD + (size_t)e*HD*ID + (size_t)nt*128*ID;
  }

  __shared__ ushort aL[64*128];   // 16KB
  __shared__ float  bF[128*64];   // 32KB (reused as epilogue transpose buf)

  const int tid = threadIdx.x;
  const int w = tid >> 6, l = tid & 63;
  const int wm = w >> 1, wn = w & 1;
  const int fr = l & 15, fko = (l >> 4) * 8;

  const ushort* aSrc[4];
  #pragma unroll
  for (int j=0;j<4;++j){
    int f = j*256 + tid;
    int L = f >> 4, s = f & 15;
    int g = s ^ (L & 15);
    int row = 2*L + (g >> 3);
    aSrc[j] = A + (size_t)row*ID + (g & 7)*8;
  }
  const float* bSrc[8];
  #pragma unroll
  for (int j=0;j<8;++j){
    int f = j*256 + tid;
    int R = f >> 4, s = f & 15;
    int g = s ^ (R & 15);
    bSrc[j] = wd + (size_t)R*ID + g*4;
  }

  f32x4 acc[4][4];
  #pragma unroll
  for (int i=0;i<4;++i)
    #pragma unroll
    for (int j=0;j<4;++j) acc[i][j] = (f32x4)0.0f;

  auto stage = [&](int kc){
    #pragma unroll
    for (int j=0;j<4;++j) gld16(aL + (size_t)(j*256 + w*64)*8, aSrc[j] + kc);
    #pragma unroll
    for (int j=0;j<8;++j) gld16(bF + (size_t)(j*256 + w*64)*4, bSrc[j] + kc);
  };

  stage(0);
  for (int kc=0; kc<ID; kc+=64){
    __syncthreads();
    #pragma unroll
    for (int ks=0; ks<2; ++ks){
      s16x8 a[4];
      #pragma unroll
      for (int mb=0; mb<4; ++mb){
        int r = wm*64 + mb*16 + fr;
        int agl = ks*4 + (fko >> 3);
        int g = ((r & 1) << 3) | agl;
        int L = r >> 1;
        int gs = g ^ (L & 15);
        a[mb] = *(const s16x8*)&aL[L*128 + gs*8];
      }
      #pragma unroll
      for (int cg=0; cg<4; ++cg){
        int R = wn*64 + cg*16 + fr;
        int gl0 = ks*8 + (fko >> 2);
        int x0 = R*64 + ((gl0 ^ (R & 15)) * 4);
        int x1 = R*64 + (((gl0+1) ^ (R & 15)) * 4);
        s16x8 bd = pack8(*(const f32x4*)&bF[x0], *(const f32x4*)&bF[x1]);
        #pragma unroll
        for (int mb=0; mb<4; ++mb){
          acc[mb][cg] = __builtin_amdgcn_mfma_f32_16x16x32_bf16(a[mb], bd, acc[mb][cg], 0, 0, 0);
        }
      }
    }
    __syncthreads();
    if (kc + 64 < ID) stage(kc + 64);
  }

  const int rq = (l >> 4) * 4;
  if (!shared_p){
    // routed: LDS-transpose epilogue -> coalesced bf16 uint4 stores
    ushort* sm = (ushort*)bF;             // 128 rows x 128 cols = 32KB exactly
    #pragma unroll
    for (int mb=0; mb<4; ++mb){
      #pragma unroll
      for (int q=0; q<4; ++q){
        int rloc = wm*64 + mb*16 + rq + q;
        #pragma unroll
        for (int cg=0; cg<4; ++cg){
          int col = wn*64 + cg*16 + fr;
          int chunk = col >> 3;
          sm[rloc*128 + ((chunk ^ (rloc & 15)) << 3) + (col & 7)] = f2bf(acc[mb][cg][q]);
        }
      }
    }
    __syncthreads();
    #pragma unroll
    for (int i=0;i<8;++i){
      int idx = i*256 + tid;
      int row = idx >> 4, j = idx & 15;
      if (mt*128 + row < cnt){
        uint4 v = *(const uint4*)&sm[row*128 + ((j ^ (row & 15)) << 3)];
        *(uint4*)(out_rows + (size_t)(abase + row)*HD + nt*128 + j*8) = v;
      }
    }
  } else {
    // shared: fp32 scalar stores to OUT (256 blocks only)
    #pragma unroll
    for (int mb=0; mb<4; ++mb){
      #pragma unroll
      for (int q=0; q<4; ++q){
        int rloc = wm*64 + mb*16 + rq + q;
        #pragma unroll
        for (int cg=0; cg<4; ++cg){
          float v = acc[mb][cg][q];
          int colg = nt*128 + wn*64 + cg*16 + fr;
          outf[(size_t)(mt*128 + rloc)*HD + colg] = v;
        }
      }
    }
  }
}

// ---------------- combine: out += sum_k topw * routed_row --------------------
__global__ __launch_bounds__(256)
void combine_kernel(const int* __restrict__ topi, const float* __restrict__ topw,
                    const int* __restrict__ pos, const int* __restrict__ ebase,
                    const ushort* __restrict__ out_rows, float* __restrict__ out)
{
  const int t = blockIdx.x;
  const int tid = threadIdx.x;
  __shared__ int rws[TK];
  __shared__ float wts[TK];
  if (tid < TK){
    int e = topi[(size_t)t*TK + tid];
    int p = pos[(size_t)t*TK + tid];
    rws[tid] = (p < CAP) ? (ebase[e] + p) : -1;
    wts[tid] = topw[(size_t)t*TK + tid];
  }
  __syncthreads();
  const int h0 = tid * 4;
  float4 acc = *(float4*)(out + (size_t)t*HD + h0);
  #pragma unroll
  for (int k=0;k<TK;++k){
    int r = rws[k];
    if (r < 0) continue;
    ushort4 v = *(const ushort4*)(out_rows + (size_t)r*HD + h0);
    float wk = wts[k];
    acc.x += wk*bf2f(v.x); acc.y += wk*bf2f(v.y);
    acc.z += wk*bf2f(v.z); acc.w += wk*bf2f(v.w);
  }
  *(float4*)(out + (size_t)t*HD + h0) = acc;
}

// ---------------- launch ------------------------------------------------------
extern "C" void kernel_launch(void* const* d_in, const int* in_sizes, int n_in,
                              void* d_out, int out_size, void* d_ws, size_t ws_size,
                              hipStream_t stream)
{
  (void)in_sizes; (void)n_in; (void)out_size; (void)ws_size;
  const float* X   = (const float*)d_in[0];
  const float* GW  = (const float*)d_in[1];
  const float* SWG = (const float*)d_in[2];
  const float* SWU = (const float*)d_in[3];
  const float* SWD = (const float*)d_in[4];
  const float* EWG = (const float*)d_in[5];
  const float* EWU = (const float*)d_in[6];
  const float* EWD = (const float*)d_in[7];
  float* OUT = (float*)d_out;

  char* p = (char*)d_ws;
  int*    topi    = (int*)p;      p += (size_t)NROUTE*4;
  float*  topw    = (float*)p;    p += (size_t)NROUTE*4;
  int*    pos     = (int*)p;      p += (size_t)NROUTE*4;
  int*    ccnt    = (int*)p;      p += (size_t)NCHUNK*NE*4;
  int*    cbase   = (int*)p;      p += (size_t)NCHUNK*NE*4;
  int*    cntC    = (int*)p;      p += 256;
  int*    ebase   = (int*)p;      p += 512;
  int*    rowlist = (int*)p;      p += (size_t)NE*CAP*4;
  ushort* Xbf     = (ushort*)p;   p += (size_t)TOK*HD*2;
  ushort* interm_r= (ushort*)p;   p += (size_t)(NROUTE+128)*ID*2;
  ushort* interm_s= (ushort*)p;   p += (size_t)TOK*ID*2;
  ushort* out_rows= (ushort*)p;   p += (size_t)NROUTE*HD*2;

  gating_kernel<<<256, 256, 0, stream>>>(X, GW, Xbf, topi, topw);
  hist_kernel<<<NCHUNK, 256, 0, stream>>>(topi, ccnt);
  scan_kernel<<<1, 64, 0, stream>>>(ccnt, cbase, cntC, ebase);
  assign_kernel<<<NCHUNK, 64, 0, stream>>>(topi, cbase, pos, rowlist);

  gateup_kernel<<<4352, 256, 0, stream>>>(Xbf, EWG, EWU, SWG, SWU,
                                          rowlist, cntC, ebase, interm_r, interm_s);
  down_kernel<<<4352, 256, 0, stream>>>(interm_r, interm_s, EWD, SWD,
                                        cntC, ebase, out_rows, OUT);

  combine_kernel<<<TOK, 256, 0, stream>>>(topi, topw, pos, ebase, out_rows, OUT);
}